// Round 9
// baseline (44.692 us; speedup 1.0000x reference)
//
#include <hip/hip_runtime.h>
#include <stdint.h>

#define DIM_IN  4096
#define DIM_OUT 4096
#define BATCH   64
// words along dim_in: 4096/64 = 64

typedef unsigned long long u64;
typedef uint32_t u32;

// ---------------------------------------------------------------------------
// Input-format detection (first 8 u32 words):
//   int32 0/1 or float 0.0/1.0 -> "word" layout (4B per bool)
//   uint8 0/1                  -> "byte" layout (1B per bool)
// Rounds 3-8: FETCH ~33.4 MB = (32 MB L2 / 67 MB masks) * 67 MB -> random-
// replacement hit rate on a word-encoded 67 MB array. Encoding also proven
// by correctness: word-path indexing on a byte array would read 4x OOB.
// ---------------------------------------------------------------------------
__device__ __forceinline__ bool is_word_fmt(const u32* __restrict__ p) {
    bool words = true;
#pragma unroll
    for (int i = 0; i < 8; ++i) {
        u32 v = p[i];
        if (v > 1u && v != 0x3F800000u) words = false;
    }
    return words;
}

// ---------------------------------------------------------------------------
// K1 (fused pack), 1040 blocks x 256 threads.
//
// blocks 0..1023: mask pack, max-occupancy + full staging.
//   Wave = (w = bid>>4, oseg = bid&15, band q = waveid). Lane owns 4 adjacent
//   columns o0 = oseg*256 + lane*4 and 16 consecutive rows w*64 + q*16 + r.
//   All 16 uint4 loads are staged before any consume -> 16 KB in flight per
//   wave for the whole load phase; 4096 independent waves (16 waves/CU, no
//   barriers, no LDS). Output: u16 band layout mp16[(w*4+q)*4096 + o]
//   (bit r of band q = row w*64+q*16+r); thread stores its 4 u16 as ONE
//   contiguous uint2 -> 512 B contiguous exclusive per wave.
//
// blocks 1024..1039: x pack via wave ballot (64 waves x 64 words).
// ---------------------------------------------------------------------------
__global__ __launch_bounds__(256) void pack_kernel(
        const void* __restrict__ masks, const void* __restrict__ x,
        u32* __restrict__ mp16, u64* __restrict__ xp) {
    const int bid = blockIdx.x;
    if (bid < 1024) {
        const bool words = is_word_fmt((const u32*)masks);
        const int w    = bid >> 4;                        // 0..63
        const int oseg = bid & 15;                        // 0..15
        const int q    = threadIdx.x >> 6;                // 0..3 (16-row band)
        const int lane = threadIdx.x & 63;
        const int o0   = oseg * 256 + lane * 4;           // 4 adjacent columns
        const int row0 = w * 64 + q * 16;

        u32 acc[4] = {0u, 0u, 0u, 0u};                    // 16 bits used each

        if (words) {
            const u32* base = (const u32*)masks + (size_t)row0 * DIM_OUT + o0;
            uint4 v[16];
#pragma unroll
            for (int r = 0; r < 16; ++r)
                v[r] = *reinterpret_cast<const uint4*>(base + (size_t)r * DIM_OUT);
#pragma unroll
            for (int r = 0; r < 16; ++r) {
                acc[0] |= (u32)(v[r].x != 0u) << r;
                acc[1] |= (u32)(v[r].y != 0u) << r;
                acc[2] |= (u32)(v[r].z != 0u) << r;
                acc[3] |= (u32)(v[r].w != 0u) << r;
            }
        } else {
            // byte layout: thread's 4 columns = one u32 per row.
            const u32* base = (const u32*)((const uint8_t*)masks
                                + (size_t)row0 * DIM_OUT + o0);
            u32 v[16];
#pragma unroll
            for (int r = 0; r < 16; ++r)
                v[r] = base[(size_t)r * (DIM_OUT / 4)];
#pragma unroll
            for (int r = 0; r < 16; ++r) {
                acc[0] |= (u32)((v[r] & 0x000000FFu) != 0u) << r;
                acc[1] |= (u32)((v[r] & 0x0000FF00u) != 0u) << r;
                acc[2] |= (u32)((v[r] & 0x00FF0000u) != 0u) << r;
                acc[3] |= (u32)((v[r] & 0xFF000000u) != 0u) << r;
            }
        }

        // mp16 band layout, stored as packed u32 pairs: index in u16 units is
        // (w*4+q)*4096 + o0  ->  u32 index = ((w*4+q)*4096 + o0) / 2.
        const size_t u32idx = (((size_t)(w * 4 + q) * DIM_OUT) + o0) >> 1;
        uint2 s;
        s.x = (acc[0] & 0xFFFFu) | (acc[1] << 16);
        s.y = (acc[2] & 0xFFFFu) | (acc[3] << 16);
        *reinterpret_cast<uint2*>(mp16 + u32idx) = s;
    } else {
        // ------------------- x pack -------------------
        const bool words = is_word_fmt((const u32*)x);
        const int bxid = bid - 1024;                          // 0..15
        const int wave = bxid * 4 + (threadIdx.x >> 6);       // 0..63
        const int lane = threadIdx.x & 63;
        const int base = wave * 64;                           // word index base

#pragma unroll 16
        for (int k = 0; k < 64; ++k) {
            const int idx = base + k;                         // 0..4095
            const size_t e = (size_t)idx * 64 + lane;         // element index
            bool pred;
            if (words) pred = ((const u32*)x)[e] != 0u;
            else       pred = ((const uint8_t*)x)[e] != 0u;
            const u64 m = __ballot(pred);
            if (lane == 0) xp[idx] = m;
        }
    }
}

// ---------------------------------------------------------------------------
// K2: out[b][o] = ((4096 - sum_w popc(xp[b][w] ^ mp[w][o])) > thr[o]) ? 1 : 0
// mp is in u16-band layout: u64 for (w,o) = bands q=0..3 at bits q*16..+15.
// Output dtype INT32. Grid: (16 o-blocks, 16 b-blocks) x 256 threads.
// ---------------------------------------------------------------------------
__global__ __launch_bounds__(256) void bnn_kernel(
        const ushort* __restrict__ mp16, const u64* __restrict__ xp,
        const int* __restrict__ thr, int* __restrict__ out) {
    const int o  = blockIdx.x * 256 + threadIdx.x;
    const int b0 = blockIdx.y * 4;

    const u64* __restrict__ x0 = xp + (size_t)(b0 + 0) * 64;
    const u64* __restrict__ x1 = xp + (size_t)(b0 + 1) * 64;
    const u64* __restrict__ x2 = xp + (size_t)(b0 + 2) * 64;
    const u64* __restrict__ x3 = xp + (size_t)(b0 + 3) * 64;

    int a0 = 0, a1 = 0, a2 = 0, a3 = 0;
#pragma unroll 8
    for (int w = 0; w < 64; ++w) {
        const size_t base = (size_t)(w * 4) * DIM_OUT + o;
        const u64 m0 = mp16[base];
        const u64 m1 = mp16[base + DIM_OUT];
        const u64 m2 = mp16[base + 2 * DIM_OUT];
        const u64 m3 = mp16[base + 3 * DIM_OUT];
        const u64 mw = m0 | (m1 << 16) | (m2 << 32) | (m3 << 48);
        a0 += __popcll(x0[w] ^ mw);
        a1 += __popcll(x1[w] ^ mw);
        a2 += __popcll(x2[w] ^ mw);
        a3 += __popcll(x3[w] ^ mw);
    }

    const int t = thr[o];
    out[(size_t)(b0 + 0) * DIM_OUT + o] = (DIM_IN - a0) > t ? 1 : 0;
    out[(size_t)(b0 + 1) * DIM_OUT + o] = (DIM_IN - a1) > t ? 1 : 0;
    out[(size_t)(b0 + 2) * DIM_OUT + o] = (DIM_IN - a2) > t ? 1 : 0;
    out[(size_t)(b0 + 3) * DIM_OUT + o] = (DIM_IN - a3) > t ? 1 : 0;
}

// ---------------------------------------------------------------------------
extern "C" void kernel_launch(void* const* d_in, const int* in_sizes, int n_in,
                              void* d_out, int out_size, void* d_ws, size_t ws_size,
                              hipStream_t stream) {
    const void* x     = d_in[0];                 // bool [64][4096]
    const void* masks = d_in[1];                 // bool [4096][4096]
    const int*  thr   = (const int*)d_in[2];     // int32 [4096]
    int* out = (int*)d_out;                      // [64][4096] int32 0/1

    u32* mp16 = (u32*)d_ws;                                      // 2 MiB (u16 bands)
    u64* xp   = (u64*)((char*)d_ws + (size_t)256 * DIM_OUT * 8); // after 2 MiB

    pack_kernel<<<dim3(1040), dim3(256), 0, stream>>>(masks, x, mp16, xp);
    bnn_kernel<<<dim3(16, 16), dim3(256), 0, stream>>>((const ushort*)mp16, xp, thr, out);
}